// Round 1
// baseline (318.296 us; speedup 1.0000x reference)
//
#include <hip/hip_runtime.h>
#include <math.h>

#define N_PTS 8192
#define TPB 256
#define RPB 8   // rows per block in phase 1

// constants
#define C_LAMBDA   2.5f
#define C_REPEL    0.15f
#define C_EPS      0.1f
#define C_NORM_EPS 1e-8f
#define C_TAUW     0.3f
#define C_TWO_PI   6.28318530717958647692f
#define C_NEG_L_LOG2E (-3.60673760222240625f)   // -2.5 * log2(e)

typedef float vf4 __attribute__((ext_vector_type(4)));

__device__ __forceinline__ float fast_exp2(float x) {
#if __has_builtin(__builtin_amdgcn_exp2f)
    return __builtin_amdgcn_exp2f(x);
#else
    return exp2f(x);
#endif
}
__device__ __forceinline__ float fast_sqrt(float x) {
#if __has_builtin(__builtin_amdgcn_sqrtf)
    return __builtin_amdgcn_sqrtf(x);
#else
    return sqrtf(x);
#endif
}
__device__ __forceinline__ float fast_rcp(float x) {
#if __has_builtin(__builtin_amdgcn_rcpf)
    return __builtin_amdgcn_rcpf(x);
#else
    return __fdividef(1.0f, x);
#endif
}
__device__ __forceinline__ float fast_log2(float x) {
#if __has_builtin(__builtin_amdgcn_logf)
    return __builtin_amdgcn_logf(x);   // v_log_f32 = log2
#else
    return log2f(x);
#endif
}

__device__ __forceinline__ float wave_reduce_sum(float v) {
    #pragma unroll
    for (int off = 32; off > 0; off >>= 1)
        v += __shfl_down(v, off, 64);
    return v;
}

// Pack j-stream: pk[j] = {theta, tau, cos, sin}; pk2[j] = {theta, tau}
__global__ void pack_kernel(const float* __restrict__ theta,
                            const float* __restrict__ tau,
                            float4* __restrict__ pk,
                            float2* __restrict__ pk2) {
    int i = blockIdx.x * blockDim.x + threadIdx.x;
    float t = theta[i];
    float u = tau[i];
    pk[i]  = make_float4(t, u, cosf(t), sinf(t));
    pk2[i] = make_float2(t, u);
}

// Phase 1: per-row reductions -> theta_out, tau_out, invsum
__global__ __launch_bounds__(TPB) void phase1_kernel(
    const float4* __restrict__ pk,
    float* __restrict__ out,        // [theta_out(N) | tau_out(N) | ...]
    float* __restrict__ invsum)
{
    const int tid  = threadIdx.x;
    const int row0 = blockIdx.x * RPB;

    float th_i[RPB], ta_i[RPB], c_i[RPB], s_i[RPB];
    #pragma unroll
    for (int r = 0; r < RPB; ++r) {
        float4 p = pk[row0 + r];
        th_i[r] = p.x; ta_i[r] = p.y; c_i[r] = p.z; s_i[r] = p.w;
    }

    float a_sum[RPB], a_x[RPB], a_y[RPB], a_t[RPB], rp_x[RPB], rp_y[RPB];
    #pragma unroll
    for (int r = 0; r < RPB; ++r) {
        a_sum[r] = 0.f; a_x[r] = 0.f; a_y[r] = 0.f;
        a_t[r] = 0.f; rp_x[r] = 0.f; rp_y[r] = 0.f;
    }

    // j-sweep with one-iteration register prefetch; diagonal flows through
    // (score=1 at j==i, repulsion self-term contributes exactly 0) and the
    // attention self-contribution is subtracted in the finalize step.
    float4 cur = pk[tid];
    #pragma unroll 2
    for (int k = 0; k < N_PTS / TPB; ++k) {
        float4 nxt = pk[(tid + (k + 1) * TPB) & (N_PTS - 1)];
        #pragma unroll
        for (int r = 0; r < RPB; ++r) {
            float ad    = fabsf(th_i[r] - cur.x);
            float dth   = fminf(ad, C_TWO_PI - ad);
            float t     = fmaf(fabsf(ta_i[r] - cur.y), C_TAUW, dth);
            float score = fast_exp2(t * C_NEG_L_LOG2E);
            a_sum[r] += score;
            a_x[r]   = fmaf(score, cur.z, a_x[r]);
            a_y[r]   = fmaf(score, cur.w, a_y[r]);
            a_t[r]   = fmaf(score, cur.y, a_t[r]);

            float d   = dth + C_EPS;
            float dx  = c_i[r] - cur.z;
            float dy  = s_i[r] - cur.w;
            float q   = fmaf(dx, dx, dy * dy);
            float nrm = fast_sqrt(q) + C_NORM_EPS;
            float inv = fast_rcp(d * d * nrm);   // REPEL folded in at finalize
            rp_x[r] = fmaf(inv, dx, rp_x[r]);
            rp_y[r] = fmaf(inv, dy, rp_y[r]);
        }
        cur = nxt;
    }

    __shared__ float red[RPB][6][TPB / 64];
    const int wave = tid >> 6;
    const int lane = tid & 63;
    #pragma unroll
    for (int r = 0; r < RPB; ++r) {
        float v0 = wave_reduce_sum(a_sum[r]);
        float v1 = wave_reduce_sum(a_x[r]);
        float v2 = wave_reduce_sum(a_y[r]);
        float v3 = wave_reduce_sum(a_t[r]);
        float v4 = wave_reduce_sum(rp_x[r]);
        float v5 = wave_reduce_sum(rp_y[r]);
        if (lane == 0) {
            red[r][0][wave] = v0; red[r][1][wave] = v1; red[r][2][wave] = v2;
            red[r][3][wave] = v3; red[r][4][wave] = v4; red[r][5][wave] = v5;
        }
    }
    __syncthreads();

    if (tid < RPB) {
        const int r = tid;
        float s = 0.f, x = 0.f, y = 0.f, t = 0.f, rx = 0.f, ry = 0.f;
        #pragma unroll
        for (int w = 0; w < TPB / 64; ++w) {
            s  += red[r][0][w]; x  += red[r][1][w]; y  += red[r][2][w];
            t  += red[r][3][w]; rx += red[r][4][w]; ry += red[r][5][w];
        }
        // subtract the j==i attention self-contribution (score == 1)
        float4 p = pk[row0 + r];
        s -= 1.0f;
        x -= p.z;
        y -= p.w;
        t -= p.y;
        float invr = 1.0f / s;
        float fx = fmaf(x, invr, C_REPEL * rx);
        float fy = fmaf(y, invr, C_REPEL * ry);
        out[row0 + r]         = atan2f(fy, fx);   // theta_out
        out[N_PTS + row0 + r] = t * invr;         // tau_out
        invsum[row0 + r]      = invr;
    }
}

// Phase 2: one block per row, 4 j's per thread, float4 nontemporal stores
__global__ __launch_bounds__(TPB) void phase2_kernel(
    const float2* __restrict__ pk2,
    const float* __restrict__ invsum,
    float* __restrict__ attn)
{
    const int i   = blockIdx.x;
    const int tid = threadIdx.x;
    float2 pi   = pk2[i];            // wave-uniform
    float th_i  = pi.x;
    float ta_i  = pi.y;
    float l2inv = fast_log2(invsum[i]);   // fold normalization into exp2
    float* __restrict__ row = attn + (size_t)i * N_PTS;
    const float4* __restrict__ pq = (const float4*)pk2;  // pq[m] = {th(2m),ta(2m),th(2m+1),ta(2m+1)}

    #pragma unroll
    for (int k = 0; k < N_PTS / (TPB * 4); ++k) {
        const int base = tid + k * TPB;       // pair-of-float2 quad index
        float4 f1 = pq[2 * base];             // j0, j0+1
        float4 f2 = pq[2 * base + 1];         // j0+2, j0+3
        const int j0 = 4 * base;

        float ad0  = fabsf(th_i - f1.x);
        float dth0 = fminf(ad0, C_TWO_PI - ad0);
        float t0   = fmaf(fabsf(ta_i - f1.y), C_TAUW, dth0);
        float v0   = fast_exp2(fmaf(t0, C_NEG_L_LOG2E, l2inv));

        float ad1  = fabsf(th_i - f1.z);
        float dth1 = fminf(ad1, C_TWO_PI - ad1);
        float t1   = fmaf(fabsf(ta_i - f1.w), C_TAUW, dth1);
        float v1   = fast_exp2(fmaf(t1, C_NEG_L_LOG2E, l2inv));

        float ad2  = fabsf(th_i - f2.x);
        float dth2 = fminf(ad2, C_TWO_PI - ad2);
        float t2   = fmaf(fabsf(ta_i - f2.y), C_TAUW, dth2);
        float v2   = fast_exp2(fmaf(t2, C_NEG_L_LOG2E, l2inv));

        float ad3  = fabsf(th_i - f2.z);
        float dth3 = fminf(ad3, C_TWO_PI - ad3);
        float t3   = fmaf(fabsf(ta_i - f2.w), C_TAUW, dth3);
        float v3   = fast_exp2(fmaf(t3, C_NEG_L_LOG2E, l2inv));

        vf4 o = {v0, v1, v2, v3};
        __builtin_nontemporal_store(o, (vf4*)(row + j0));
    }

    // diagonal: overwrite attn[i][i] = 0 after all row stores are visible
    __syncthreads();
    if (tid == 0) row[i] = 0.0f;
}

extern "C" void kernel_launch(void* const* d_in, const int* in_sizes, int n_in,
                              void* d_out, int out_size, void* d_ws, size_t ws_size,
                              hipStream_t stream) {
    const float* theta = (const float*)d_in[0];
    const float* tau   = (const float*)d_in[1];

    float4* pk     = (float4*)d_ws;                          // 128 KB
    float2* pk2    = (float2*)((char*)d_ws + 128 * 1024);    //  64 KB
    float*  invsum = (float*)((char*)d_ws + 192 * 1024);     //  32 KB
    float*  out    = (float*)d_out;
    float*  attn   = out + 2 * N_PTS;

    pack_kernel<<<N_PTS / 256, 256, 0, stream>>>(theta, tau, pk, pk2);
    phase1_kernel<<<N_PTS / RPB, TPB, 0, stream>>>(pk, out, invsum);
    phase2_kernel<<<N_PTS, TPB, 0, stream>>>(pk2, invsum, attn);
}

// Round 2
// 280.101 us; speedup vs baseline: 1.1364x; 1.1364x over previous
//
#include <hip/hip_runtime.h>
#include <math.h>

#define N_PTS 8192
#define TPB 256
#define RPB 4   // rows per block (RPB=8 measured -19us regression in R1; keep 4)

// constants
#define C_LAMBDA   2.5f
#define C_REPEL    0.15f
#define C_EPS      0.1f
#define C_NORM_EPS 1e-8f
#define C_TAUW     0.3f
#define C_TWO_PI   6.28318530717958647692f
#define C_NEG_L_LOG2E (-3.60673760222240625f)   // -2.5 * log2(e)

typedef float vf4 __attribute__((ext_vector_type(4)));

__device__ __forceinline__ float fast_exp2(float x) {
#if __has_builtin(__builtin_amdgcn_exp2f)
    return __builtin_amdgcn_exp2f(x);
#else
    return exp2f(x);
#endif
}
__device__ __forceinline__ float fast_sqrt(float x) {
#if __has_builtin(__builtin_amdgcn_sqrtf)
    return __builtin_amdgcn_sqrtf(x);
#else
    return sqrtf(x);
#endif
}
__device__ __forceinline__ float fast_rcp(float x) {
#if __has_builtin(__builtin_amdgcn_rcpf)
    return __builtin_amdgcn_rcpf(x);
#else
    return __fdividef(1.0f, x);
#endif
}
__device__ __forceinline__ float fast_log2(float x) {
#if __has_builtin(__builtin_amdgcn_logf)
    return __builtin_amdgcn_logf(x);   // v_log_f32 = log2
#else
    return log2f(x);
#endif
}

__device__ __forceinline__ float wave_reduce_sum(float v) {
    #pragma unroll
    for (int off = 32; off > 0; off >>= 1)
        v += __shfl_down(v, off, 64);
    return v;
}

// Pack j-stream: pk[j] = {theta, tau, cos, sin}; pk2[j] = {theta, tau}
__global__ void pack_kernel(const float* __restrict__ theta,
                            const float* __restrict__ tau,
                            float4* __restrict__ pk,
                            float2* __restrict__ pk2) {
    int i = blockIdx.x * blockDim.x + threadIdx.x;
    float t = theta[i];
    float u = tau[i];
    pk[i]  = make_float4(t, u, cosf(t), sinf(t));
    pk2[i] = make_float2(t, u);
}

// Fused: pass A = per-row reductions (theta_out, tau_out, invsum);
//        pass B = normalized attn row writeback (float4 stores).
__global__ __launch_bounds__(TPB) void fused_kernel(
    const float4* __restrict__ pk,
    const float4* __restrict__ pq,   // (float4*)pk2: {th(2m),ta(2m),th(2m+1),ta(2m+1)}
    float* __restrict__ out)         // [theta_out(N) | tau_out(N) | attn(N*N)]
{
    const int tid  = threadIdx.x;
    const int row0 = blockIdx.x * RPB;

    float th_i[RPB], ta_i[RPB], c_i[RPB], s_i[RPB];
    #pragma unroll
    for (int r = 0; r < RPB; ++r) {
        float4 p = pk[row0 + r];
        th_i[r] = p.x; ta_i[r] = p.y; c_i[r] = p.z; s_i[r] = p.w;
    }

    float a_sum[RPB], a_x[RPB], a_y[RPB], a_t[RPB], rp_x[RPB], rp_y[RPB];
    #pragma unroll
    for (int r = 0; r < RPB; ++r) {
        a_sum[r] = 0.f; a_x[r] = 0.f; a_y[r] = 0.f;
        a_t[r] = 0.f; rp_x[r] = 0.f; rp_y[r] = 0.f;
    }

    // ---- pass A: j-sweep with one-iteration register prefetch ----
    // diagonal flows through (score=1 at j==i, repulsion self-term is exactly 0)
    // and the attention self-contribution is subtracted in the finalize step.
    float4 cur = pk[tid];
    #pragma unroll 2
    for (int k = 0; k < N_PTS / TPB; ++k) {
        float4 nxt = pk[(tid + (k + 1) * TPB) & (N_PTS - 1)];
        #pragma unroll
        for (int r = 0; r < RPB; ++r) {
            float ad    = fabsf(th_i[r] - cur.x);
            float dth   = fminf(ad, C_TWO_PI - ad);
            float t     = fmaf(fabsf(ta_i[r] - cur.y), C_TAUW, dth);
            float score = fast_exp2(t * C_NEG_L_LOG2E);
            a_sum[r] += score;
            a_x[r]   = fmaf(score, cur.z, a_x[r]);
            a_y[r]   = fmaf(score, cur.w, a_y[r]);
            a_t[r]   = fmaf(score, cur.y, a_t[r]);

            float d   = dth + C_EPS;
            float dx  = c_i[r] - cur.z;
            float dy  = s_i[r] - cur.w;
            float q   = fmaf(dx, dx, dy * dy);
            float nrm = fast_sqrt(q) + C_NORM_EPS;
            float inv = fast_rcp(d * d * nrm);   // REPEL folded in at finalize
            rp_x[r] = fmaf(inv, dx, rp_x[r]);
            rp_y[r] = fmaf(inv, dy, rp_y[r]);
        }
        cur = nxt;
    }

    __shared__ float red[RPB][6][TPB / 64];
    __shared__ float l2s[RPB];
    const int wave = tid >> 6;
    const int lane = tid & 63;
    #pragma unroll
    for (int r = 0; r < RPB; ++r) {
        float v0 = wave_reduce_sum(a_sum[r]);
        float v1 = wave_reduce_sum(a_x[r]);
        float v2 = wave_reduce_sum(a_y[r]);
        float v3 = wave_reduce_sum(a_t[r]);
        float v4 = wave_reduce_sum(rp_x[r]);
        float v5 = wave_reduce_sum(rp_y[r]);
        if (lane == 0) {
            red[r][0][wave] = v0; red[r][1][wave] = v1; red[r][2][wave] = v2;
            red[r][3][wave] = v3; red[r][4][wave] = v4; red[r][5][wave] = v5;
        }
    }
    __syncthreads();

    if (tid < RPB) {
        const int r = tid;
        float s = 0.f, x = 0.f, y = 0.f, t = 0.f, rx = 0.f, ry = 0.f;
        #pragma unroll
        for (int w = 0; w < TPB / 64; ++w) {
            s  += red[r][0][w]; x  += red[r][1][w]; y  += red[r][2][w];
            t  += red[r][3][w]; rx += red[r][4][w]; ry += red[r][5][w];
        }
        // subtract the j==i attention self-contribution (score == 1)
        float4 p = pk[row0 + r];
        s -= 1.0f;
        x -= p.z;
        y -= p.w;
        t -= p.y;
        float invr = 1.0f / s;
        float fx = fmaf(x, invr, C_REPEL * rx);
        float fy = fmaf(y, invr, C_REPEL * ry);
        out[row0 + r]         = atan2f(fy, fx);   // theta_out
        out[N_PTS + row0 + r] = t * invr;         // tau_out
        l2s[r] = fast_log2(invr);                 // fold normalization into exp2
    }
    __syncthreads();

    // ---- pass B: write normalized attn rows, 4 j's per thread, float4 stores ----
    float l2r[RPB];
    #pragma unroll
    for (int r = 0; r < RPB; ++r) l2r[r] = l2s[r];

    float* __restrict__ attn = out + 2 * N_PTS;

    #pragma unroll 2
    for (int k = 0; k < N_PTS / (TPB * 4); ++k) {
        const int base = tid + k * TPB;       // pair-of-float2 quad index
        float4 f1 = pq[2 * base];             // j0, j0+1
        float4 f2 = pq[2 * base + 1];         // j0+2, j0+3
        const int j0 = 4 * base;
        #pragma unroll
        for (int r = 0; r < RPB; ++r) {
            float ad0  = fabsf(th_i[r] - f1.x);
            float dth0 = fminf(ad0, C_TWO_PI - ad0);
            float t0   = fmaf(fabsf(ta_i[r] - f1.y), C_TAUW, dth0);
            float v0   = fast_exp2(fmaf(t0, C_NEG_L_LOG2E, l2r[r]));

            float ad1  = fabsf(th_i[r] - f1.z);
            float dth1 = fminf(ad1, C_TWO_PI - ad1);
            float t1   = fmaf(fabsf(ta_i[r] - f1.w), C_TAUW, dth1);
            float v1   = fast_exp2(fmaf(t1, C_NEG_L_LOG2E, l2r[r]));

            float ad2  = fabsf(th_i[r] - f2.x);
            float dth2 = fminf(ad2, C_TWO_PI - ad2);
            float t2   = fmaf(fabsf(ta_i[r] - f2.y), C_TAUW, dth2);
            float v2   = fast_exp2(fmaf(t2, C_NEG_L_LOG2E, l2r[r]));

            float ad3  = fabsf(th_i[r] - f2.z);
            float dth3 = fminf(ad3, C_TWO_PI - ad3);
            float t3   = fmaf(fabsf(ta_i[r] - f2.w), C_TAUW, dth3);
            float v3   = fast_exp2(fmaf(t3, C_NEG_L_LOG2E, l2r[r]));

            vf4 o = {v0, v1, v2, v3};
            *(vf4*)(attn + (size_t)(row0 + r) * N_PTS + j0) = o;
        }
    }

    // diagonal: overwrite attn[i][i] = 0 after all row stores (workgroup fence)
    __syncthreads();
    if (tid < RPB) {
        const int i = row0 + tid;
        attn[(size_t)i * N_PTS + i] = 0.0f;
    }
}

extern "C" void kernel_launch(void* const* d_in, const int* in_sizes, int n_in,
                              void* d_out, int out_size, void* d_ws, size_t ws_size,
                              hipStream_t stream) {
    const float* theta = (const float*)d_in[0];
    const float* tau   = (const float*)d_in[1];

    float4* pk  = (float4*)d_ws;                          // 128 KB
    float2* pk2 = (float2*)((char*)d_ws + 128 * 1024);    //  64 KB
    float*  out = (float*)d_out;

    pack_kernel<<<N_PTS / 256, 256, 0, stream>>>(theta, tau, pk, pk2);
    fused_kernel<<<N_PTS / RPB, TPB, 0, stream>>>(pk, (const float4*)pk2, out);
}

// Round 3
// 274.753 us; speedup vs baseline: 1.1585x; 1.0195x over previous
//
#include <hip/hip_runtime.h>
#include <math.h>

#define N_PTS 8192
#define TPB 256
#define RPB 4   // rows per block (RPB=8 measured -19us regression in R1; keep 4)

// constants
#define C_LAMBDA   2.5f
#define C_REPEL    0.15f
#define C_EPS      0.1f
#define C_NORM_EPS 1e-8f
#define C_TAUW     0.3f
#define C_TWO_PI   6.28318530717958647692f
#define C_NEG_L_LOG2E (-3.60673760222240625f)   // -2.5 * log2(e)
#define C_Q_DELTA  1e-16f   // rsqrt guard: q==0 (diagonal) stays finite

typedef float vf4 __attribute__((ext_vector_type(4)));

__device__ __forceinline__ float fast_exp2(float x) {
#if __has_builtin(__builtin_amdgcn_exp2f)
    return __builtin_amdgcn_exp2f(x);
#else
    return exp2f(x);
#endif
}
__device__ __forceinline__ float fast_rsqrt(float x) {
#if __has_builtin(__builtin_amdgcn_rsqf)
    return __builtin_amdgcn_rsqf(x);
#else
    return rsqrtf(x);
#endif
}
__device__ __forceinline__ float fast_log2(float x) {
#if __has_builtin(__builtin_amdgcn_logf)
    return __builtin_amdgcn_logf(x);   // v_log_f32 = log2
#else
    return log2f(x);
#endif
}

__device__ __forceinline__ float wave_reduce_sum(float v) {
    #pragma unroll
    for (int off = 32; off > 0; off >>= 1)
        v += __shfl_down(v, off, 64);
    return v;
}

// Pack j-stream: pk[j] = {theta, tau, cos, sin}; pk2[j] = {theta, tau}
__global__ void pack_kernel(const float* __restrict__ theta,
                            const float* __restrict__ tau,
                            float4* __restrict__ pk,
                            float2* __restrict__ pk2) {
    int i = blockIdx.x * blockDim.x + threadIdx.x;
    float t = theta[i];
    float u = tau[i];
    pk[i]  = make_float4(t, u, cosf(t), sinf(t));
    pk2[i] = make_float2(t, u);
}

// Fused: pass A = per-row reductions (theta_out, tau_out, invsum);
//        pass B = normalized attn row writeback (float4 stores).
__global__ __launch_bounds__(TPB) void fused_kernel(
    const float4* __restrict__ pk,
    const float4* __restrict__ pq,   // (float4*)pk2: {th(2m),ta(2m),th(2m+1),ta(2m+1)}
    float* __restrict__ out)         // [theta_out(N) | tau_out(N) | attn(N*N)]
{
    const int tid  = threadIdx.x;
    const int row0 = blockIdx.x * RPB;

    float th_i[RPB], ta_i[RPB], c_i[RPB], s_i[RPB];
    #pragma unroll
    for (int r = 0; r < RPB; ++r) {
        float4 p = pk[row0 + r];
        th_i[r] = p.x; ta_i[r] = p.y; c_i[r] = p.z; s_i[r] = p.w;
    }

    float a_sum[RPB], a_x[RPB], a_y[RPB], a_t[RPB], rp_x[RPB], rp_y[RPB];
    #pragma unroll
    for (int r = 0; r < RPB; ++r) {
        a_sum[r] = 0.f; a_x[r] = 0.f; a_y[r] = 0.f;
        a_t[r] = 0.f; rp_x[r] = 0.f; rp_y[r] = 0.f;
    }

    // ---- pass A: j-sweep; compiler-scheduled loads (no manual prefetch) ----
    // diagonal flows through (score=1 at j==i, repulsion self-term is exactly 0
    // because dx=dy=0 and rsqrt stays finite via C_Q_DELTA) and the attention
    // self-contribution is subtracted in the finalize step.
    #pragma unroll 4
    for (int k = 0; k < N_PTS / TPB; ++k) {
        float4 cur = pk[tid + k * TPB];
        #pragma unroll
        for (int r = 0; r < RPB; ++r) {
            float ad    = fabsf(th_i[r] - cur.x);
            float dth   = fminf(ad, C_TWO_PI - ad);
            float t     = fmaf(fabsf(ta_i[r] - cur.y), C_TAUW, dth);
            float score = fast_exp2(t * C_NEG_L_LOG2E);
            a_sum[r] += score;
            a_x[r]   = fmaf(score, cur.z, a_x[r]);
            a_y[r]   = fmaf(score, cur.w, a_y[r]);
            a_t[r]   = fmaf(score, cur.y, a_t[r]);

            float d   = dth + C_EPS;
            float dx  = c_i[r] - cur.z;
            float dy  = s_i[r] - cur.w;
            float q   = fmaf(dx, dx, dy * dy);
            float d2  = d * d;
            // 1/(d^2 * (sqrt(q)+1e-8)) ~= rsqrt((q + delta) * d^4): one trans
            // op instead of two (sqrt+rcp); REPEL folded in at finalize.
            float inv = fast_rsqrt((q + C_Q_DELTA) * (d2 * d2));
            rp_x[r] = fmaf(inv, dx, rp_x[r]);
            rp_y[r] = fmaf(inv, dy, rp_y[r]);
        }
    }

    __shared__ float red[RPB][6][TPB / 64];
    __shared__ float l2s[RPB];
    const int wave = tid >> 6;
    const int lane = tid & 63;
    #pragma unroll
    for (int r = 0; r < RPB; ++r) {
        float v0 = wave_reduce_sum(a_sum[r]);
        float v1 = wave_reduce_sum(a_x[r]);
        float v2 = wave_reduce_sum(a_y[r]);
        float v3 = wave_reduce_sum(a_t[r]);
        float v4 = wave_reduce_sum(rp_x[r]);
        float v5 = wave_reduce_sum(rp_y[r]);
        if (lane == 0) {
            red[r][0][wave] = v0; red[r][1][wave] = v1; red[r][2][wave] = v2;
            red[r][3][wave] = v3; red[r][4][wave] = v4; red[r][5][wave] = v5;
        }
    }
    __syncthreads();

    if (tid < RPB) {
        const int r = tid;
        float s = 0.f, x = 0.f, y = 0.f, t = 0.f, rx = 0.f, ry = 0.f;
        #pragma unroll
        for (int w = 0; w < TPB / 64; ++w) {
            s  += red[r][0][w]; x  += red[r][1][w]; y  += red[r][2][w];
            t  += red[r][3][w]; rx += red[r][4][w]; ry += red[r][5][w];
        }
        // subtract the j==i attention self-contribution (score == 1)
        float4 p = pk[row0 + r];
        s -= 1.0f;
        x -= p.z;
        y -= p.w;
        t -= p.y;
        float invr = 1.0f / s;
        float fx = fmaf(x, invr, C_REPEL * rx);
        float fy = fmaf(y, invr, C_REPEL * ry);
        out[row0 + r]         = atan2f(fy, fx);   // theta_out
        out[N_PTS + row0 + r] = t * invr;         // tau_out
        l2s[r] = fast_log2(invr);                 // fold normalization into exp2
    }
    __syncthreads();

    // ---- pass B: write normalized attn rows, 4 j's per thread, float4 stores ----
    float l2r[RPB];
    #pragma unroll
    for (int r = 0; r < RPB; ++r) l2r[r] = l2s[r];

    float* __restrict__ attn = out + 2 * N_PTS;

    #pragma unroll 2
    for (int k = 0; k < N_PTS / (TPB * 4); ++k) {
        const int base = tid + k * TPB;       // pair-of-float2 quad index
        float4 f1 = pq[2 * base];             // j0, j0+1
        float4 f2 = pq[2 * base + 1];         // j0+2, j0+3
        const int j0 = 4 * base;
        #pragma unroll
        for (int r = 0; r < RPB; ++r) {
            float ad0  = fabsf(th_i[r] - f1.x);
            float dth0 = fminf(ad0, C_TWO_PI - ad0);
            float t0   = fmaf(fabsf(ta_i[r] - f1.y), C_TAUW, dth0);
            float v0   = fast_exp2(fmaf(t0, C_NEG_L_LOG2E, l2r[r]));

            float ad1  = fabsf(th_i[r] - f1.z);
            float dth1 = fminf(ad1, C_TWO_PI - ad1);
            float t1   = fmaf(fabsf(ta_i[r] - f1.w), C_TAUW, dth1);
            float v1   = fast_exp2(fmaf(t1, C_NEG_L_LOG2E, l2r[r]));

            float ad2  = fabsf(th_i[r] - f2.x);
            float dth2 = fminf(ad2, C_TWO_PI - ad2);
            float t2   = fmaf(fabsf(ta_i[r] - f2.y), C_TAUW, dth2);
            float v2   = fast_exp2(fmaf(t2, C_NEG_L_LOG2E, l2r[r]));

            float ad3  = fabsf(th_i[r] - f2.z);
            float dth3 = fminf(ad3, C_TWO_PI - ad3);
            float t3   = fmaf(fabsf(ta_i[r] - f2.w), C_TAUW, dth3);
            float v3   = fast_exp2(fmaf(t3, C_NEG_L_LOG2E, l2r[r]));

            vf4 o = {v0, v1, v2, v3};
            *(vf4*)(attn + (size_t)(row0 + r) * N_PTS + j0) = o;
        }
    }

    // diagonal: overwrite attn[i][i] = 0 after all row stores (workgroup fence)
    __syncthreads();
    if (tid < RPB) {
        const int i = row0 + tid;
        attn[(size_t)i * N_PTS + i] = 0.0f;
    }
}

extern "C" void kernel_launch(void* const* d_in, const int* in_sizes, int n_in,
                              void* d_out, int out_size, void* d_ws, size_t ws_size,
                              hipStream_t stream) {
    const float* theta = (const float*)d_in[0];
    const float* tau   = (const float*)d_in[1];

    float4* pk  = (float4*)d_ws;                          // 128 KB
    float2* pk2 = (float2*)((char*)d_ws + 128 * 1024);    //  64 KB
    float*  out = (float*)d_out;

    pack_kernel<<<N_PTS / 256, 256, 0, stream>>>(theta, tau, pk, pk2);
    fused_kernel<<<N_PTS / RPB, TPB, 0, stream>>>(pk, (const float4*)pk2, out);
}